// Round 1
// baseline (582.039 us; speedup 1.0000x reference)
//
#include <hip/hip_runtime.h>
#include <hip/hip_bf16.h>

// AttentionLayer: T=128, N=2048, D=256, w=3
// out[i] = x[i]                        for i < 3
// out[i,n,:] = sum_j p[i-3+j,n] * x[i-3+j,n,:]   for i >= 3
// where p[t,:] = softmax_n( sum_e proj[e]*tanh( (x[t] @ W)[n,e] ) )

#define T_DIM 128
#define N_DIM 2048
#define D_DIM 256
#define TS 127              // number of s/p slices (t = 0..126)
#define M_TOT (TS * N_DIM)  // 260096 rows in the fused GEMM

typedef __attribute__((ext_vector_type(8))) short bf16x8;
typedef __attribute__((ext_vector_type(4))) float f32x4;

__device__ inline short f2bf(float f) {
  union { float f; unsigned u; } v; v.f = f;
  unsigned r = v.u + 0x7FFFu + ((v.u >> 16) & 1u);  // round-nearest-even
  return (short)(r >> 16);
}

// ---------------- k0: W (fp32, d x e) -> Wt (bf16, e x d) ----------------
__global__ __launch_bounds__(256) void prep_kernel(const float* __restrict__ W,
                                                   short* __restrict__ Wt) {
  int id = blockIdx.x * 256 + threadIdx.x;   // 65536 total
  int d = id >> 8;
  int e = id & 255;
  Wt[e * 256 + d] = f2bf(W[d * 256 + e]);
}

// ---------------- k1: fused GEMM + tanh + proj-reduce -> s[m] ------------
// C-tile 128(m) x 128(e), BK=32, 4 waves each 64x64 (4x4 frags of 16x16x32)
#define BM 128
#define BE 128
#define BK 32
#define LDSP 40  // padded LDS row stride (bf16 elems): 80B rows

__global__ __launch_bounds__(256) void gemm_s_kernel(const float* __restrict__ x,
                                                     const short* __restrict__ Wt,
                                                     const float* __restrict__ proj,
                                                     float* __restrict__ s) {
  __shared__ short As[BM * LDSP];
  __shared__ short Bs[BE * LDSP];
  __shared__ float sred[BM][2];

  const int tid = threadIdx.x;
  const int m0 = blockIdx.x * BM;
  const int e0 = blockIdx.y * BE;
  const int lane = tid & 63;
  const int w = tid >> 6;
  const int quad = lane >> 4;
  const int l15 = lane & 15;
  const int wr = (w >> 1) * 64;  // wave row offset in tile
  const int we = (w & 1) * 64;   // wave col (e) offset in tile

  f32x4 acc[4][4] = {};

  for (int kk = 0; kk < D_DIM; kk += BK) {
    __syncthreads();
    // stage A: 128 rows x 32 k (fp32 -> bf16). 1024 float4 slots / 256 thr.
#pragma unroll
    for (int it = 0; it < 4; ++it) {
      int slot = tid + it * 256;
      int row = slot >> 3, f4 = slot & 7;
      const float4 v = *(const float4*)(x + (size_t)(m0 + row) * D_DIM + kk + f4 * 4);
      short4 b;
      b.x = f2bf(v.x); b.y = f2bf(v.y); b.z = f2bf(v.z); b.w = f2bf(v.w);
      *(short4*)(As + row * LDSP + f4 * 4) = b;
    }
    // stage B: 128 e-rows x 32 k (already bf16). 512 16B slots / 256 thr.
#pragma unroll
    for (int it = 0; it < 2; ++it) {
      int slot = tid + it * 256;
      int row = slot >> 2, seg = slot & 3;
      uint4 v = *(const uint4*)(Wt + (size_t)(e0 + row) * D_DIM + kk + seg * 8);
      *(uint4*)(Bs + row * LDSP + seg * 8) = v;
    }
    __syncthreads();

    bf16x8 a[4], b[4];
#pragma unroll
    for (int i = 0; i < 4; ++i)
      a[i] = *(const bf16x8*)(As + (wr + i * 16 + l15) * LDSP + quad * 8);
#pragma unroll
    for (int j = 0; j < 4; ++j)
      b[j] = *(const bf16x8*)(Bs + (we + j * 16 + l15) * LDSP + quad * 8);
#pragma unroll
    for (int i = 0; i < 4; ++i)
#pragma unroll
      for (int j = 0; j < 4; ++j)
        acc[i][j] = __builtin_amdgcn_mfma_f32_16x16x32_bf16(a[i], b[j], acc[i][j], 0, 0, 0);
  }

  // epilogue: val[m] = sum_e tanh(C[m][e]) * proj[e]  (per block-e-half)
  float pj[4];
#pragma unroll
  for (int j = 0; j < 4; ++j) pj[j] = proj[e0 + we + j * 16 + l15];

#pragma unroll
  for (int i = 0; i < 4; ++i) {
#pragma unroll
    for (int r = 0; r < 4; ++r) {
      float val = 0.f;
#pragma unroll
      for (int j = 0; j < 4; ++j) val += tanhf(acc[i][j][r]) * pj[j];
      // reduce across the 16 lanes of this quad (they hold 16 different e)
#pragma unroll
      for (int off = 1; off < 16; off <<= 1) val += __shfl_xor(val, off);
      if (l15 == 0) sred[wr + i * 16 + quad * 4 + r][w & 1] = val;
    }
  }
  __syncthreads();
  if (tid < BM) atomicAdd(&s[m0 + tid], sred[tid][0] + sred[tid][1]);
}

// ---------------- k2: softmax over n (2048) per t ------------------------
__global__ __launch_bounds__(256) void softmax_kernel(const float* __restrict__ s,
                                                      float* __restrict__ p) {
  const int t = blockIdx.x;
  const int tid = threadIdx.x;
  const float* row = s + (size_t)t * N_DIM;
  float v[8];
  float mx = -1e30f;
#pragma unroll
  for (int k = 0; k < 8; ++k) {
    v[k] = row[tid + k * 256];
    mx = fmaxf(mx, v[k]);
  }
#pragma unroll
  for (int off = 1; off < 64; off <<= 1) mx = fmaxf(mx, __shfl_xor(mx, off));
  __shared__ float redm[4];
  if ((tid & 63) == 0) redm[tid >> 6] = mx;
  __syncthreads();
  mx = fmaxf(fmaxf(redm[0], redm[1]), fmaxf(redm[2], redm[3]));

  float sum = 0.f;
#pragma unroll
  for (int k = 0; k < 8; ++k) {
    v[k] = __expf(v[k] - mx);
    sum += v[k];
  }
#pragma unroll
  for (int off = 1; off < 64; off <<= 1) sum += __shfl_xor(sum, off);
  __shared__ float reds[4];
  if ((tid & 63) == 0) reds[tid >> 6] = sum;
  __syncthreads();
  sum = reds[0] + reds[1] + reds[2] + reds[3];
  float inv = 1.0f / sum;
#pragma unroll
  for (int k = 0; k < 8; ++k) p[(size_t)t * N_DIM + tid + k * 256] = v[k] * inv;
}

// ---------------- k3: streaming output with rolling window ---------------
__global__ __launch_bounds__(256) void out_kernel(const float* __restrict__ x,
                                                  const float* __restrict__ p,
                                                  float* __restrict__ out) {
  const int gid = blockIdx.x * 256 + threadIdx.x;  // 131072 = 2048 * 64
  const int n = gid >> 6;
  const int d4 = gid & 63;
  const size_t base = (size_t)n * D_DIM + d4 * 4;
  const size_t tstride = (size_t)N_DIM * D_DIM;

  float4 x0 = {}, x1 = {}, x2 = {};
  float p0 = 0.f, p1 = 0.f, p2 = 0.f;
  for (int t = 0; t < T_DIM; ++t) {
    const float4 xc = *(const float4*)(x + t * tstride + base);
    const float pc = (t < TS) ? p[(size_t)t * N_DIM + n] : 0.f;
    float4 o;
    if (t >= 3) {
      o.x = p0 * x0.x + p1 * x1.x + p2 * x2.x;
      o.y = p0 * x0.y + p1 * x1.y + p2 * x2.y;
      o.z = p0 * x0.z + p1 * x1.z + p2 * x2.z;
      o.w = p0 * x0.w + p1 * x1.w + p2 * x2.w;
    } else {
      o = xc;
    }
    *(float4*)(out + t * tstride + base) = o;
    x0 = x1; x1 = x2; x2 = xc;
    p0 = p1; p1 = p2; p2 = pc;
  }
}

extern "C" void kernel_launch(void* const* d_in, const int* in_sizes, int n_in,
                              void* d_out, int out_size, void* d_ws, size_t ws_size,
                              hipStream_t stream) {
  const float* x = (const float*)d_in[0];     // (128, 2048, 256) fp32
  const float* W = (const float*)d_in[1];     // (256, 256) fp32
  const float* proj = (const float*)d_in[2];  // (256, 1) fp32
  // d_in[3] = attention_width = 3 (hardcoded)
  float* out = (float*)d_out;

  // workspace layout
  char* ws = (char*)d_ws;
  short* Wt = (short*)ws;                               // 65536 bf16 = 128 KB
  float* s = (float*)(ws + 131072);                     // 260096 f32 ~ 1 MB
  float* p = (float*)(ws + 131072 + 1040384);           // 260096 f32 ~ 1 MB

  // k0: transpose+convert W, zero s (ws is poisoned before every call)
  hipLaunchKernelGGL(prep_kernel, dim3(256), dim3(256), 0, stream, W, Wt);
  hipMemsetAsync(s, 0, (size_t)M_TOT * sizeof(float), stream);

  // k1: s[t,n] = sum_e proj[e]*tanh((x[t] @ W)[n,e])
  hipLaunchKernelGGL(gemm_s_kernel, dim3(M_TOT / BM, D_DIM / BE), dim3(256), 0, stream,
                     x, Wt, proj, s);

  // k2: p[t,:] = softmax_n(s[t,:])
  hipLaunchKernelGGL(softmax_kernel, dim3(TS), dim3(256), 0, stream, s, p);

  // k3: stream the output
  hipLaunchKernelGGL(out_kernel, dim3((N_DIM * 64) / 256), dim3(256), 0, stream,
                     x, p, out);
}